// Round 8
// baseline (469.389 us; speedup 1.0000x reference)
//
#include <hip/hip_runtime.h>
#include <hip/hip_bf16.h>

using bf16   = __hip_bfloat16;
using bf16x8 = __attribute__((ext_vector_type(8))) __bf16;
using f32x4  = __attribute__((ext_vector_type(4))) float;
using short8 = __attribute__((ext_vector_type(8))) short;

__device__ __forceinline__ unsigned short f2b(float x) {
  union { bf16 b; unsigned short u; } t; t.b = __float2bfloat16(x); return t.u;
}
__device__ __forceinline__ float b2f(unsigned short u) {
  union { unsigned int i; float f; } t; t.i = ((unsigned int)u) << 16; return t.f;
}

typedef __attribute__((address_space(1))) const unsigned int* gas1_t;
typedef __attribute__((address_space(3))) unsigned int* las3_t;
__device__ __forceinline__ void gload16(const void* g, void* l) {
  __builtin_amdgcn_global_load_lds((gas1_t)g, (las3_t)l, 16, 0, 0);
}

// ---------------- small f32->bf16 casts (no vp cast anymore) ----------------
__global__ __launch_bounds__(256) void k_cast_all(
    const float* __restrict__ s0, bf16* __restrict__ d0,            // sa_in 196608
    const float* __restrict__ s1, bf16* __restrict__ d1,            // sa_out 65536
    const float* __restrict__ s2, bf16* __restrict__ d2,            // ca_in 196608
    const float* __restrict__ s3, bf16* __restrict__ d3,            // ca_out 65536
    const float* __restrict__ s4, bf16* __restrict__ d4,            // w1 262144
    const float* __restrict__ s5, bf16* __restrict__ d5,            // w2 262144
    const float* __restrict__ s6, bf16* __restrict__ d6) {          // emo 131072
  int i = blockIdx.x * 256 + threadIdx.x;
  int str = gridDim.x * 256;
  for (; i < 1179648; i += str) {
    int j = i;
    const float* s; bf16* d; int off;
    if      (j <  196608) { s = s0; d = d0; off = j; }
    else if (j <  262144) { s = s1; d = d1; off = j - 196608; }
    else if (j <  458752) { s = s2; d = d2; off = j - 262144; }
    else if (j <  524288) { s = s3; d = d3; off = j - 458752; }
    else if (j <  786432) { s = s4; d = d4; off = j - 524288; }
    else if (j < 1048576) { s = s5; d = d5; off = j - 786432; }
    else                  { s = s6; d = d6; off = j - 1048576; }
    float4 v = ((const float4*)s)[off];
    ushort4 u; u.x = f2b(v.x); u.y = f2b(v.y); u.z = f2b(v.z); u.w = f2b(v.w);
    ((ushort4*)d)[off] = u;
  }
}

// ---------------- fused token+pos embedding + LayerNorm1 ----------------
__global__ __launch_bounds__(256) void k_embed_ln(const int* __restrict__ ids, const float* __restrict__ tok,
                                                  const float* __restrict__ pos, const float* __restrict__ g,
                                                  const float* __restrict__ bb, float* __restrict__ x,
                                                  float* __restrict__ emb, bf16* __restrict__ o) {
  int wid = threadIdx.x >> 6, lane = threadIdx.x & 63;
  int row = blockIdx.x * 4 + wid;
  int tt = row & 127;
  int id = ids[row];
  int d = lane * 8;
  float4 e0 = *(const float4*)&tok[(size_t)id * 512 + d];
  float4 e1 = *(const float4*)&tok[(size_t)id * 512 + d + 4];
  float4 p0 = *(const float4*)&pos[(size_t)tt * 512 + d];
  float4 p1 = *(const float4*)&pos[(size_t)tt * 512 + d + 4];
  *(float4*)&emb[(size_t)row * 512 + d]     = e0;
  *(float4*)&emb[(size_t)row * 512 + d + 4] = e1;
  float4 v0; v0.x = e0.x + p0.x; v0.y = e0.y + p0.y; v0.z = e0.z + p0.z; v0.w = e0.w + p0.w;
  float4 v1; v1.x = e1.x + p1.x; v1.y = e1.y + p1.y; v1.z = e1.z + p1.z; v1.w = e1.w + p1.w;
  *(float4*)&x[(size_t)row * 512 + d]     = v0;
  *(float4*)&x[(size_t)row * 512 + d + 4] = v1;
  float s = v0.x + v0.y + v0.z + v0.w + v1.x + v1.y + v1.z + v1.w;
  float q = v0.x*v0.x + v0.y*v0.y + v0.z*v0.z + v0.w*v0.w
          + v1.x*v1.x + v1.y*v1.y + v1.z*v1.z + v1.w*v1.w;
#pragma unroll
  for (int t = 32; t; t >>= 1) { s += __shfl_xor(s, t); q += __shfl_xor(q, t); }
  float mean = s * (1.f / 512.f);
  float var  = q * (1.f / 512.f) - mean * mean;
  float rstd = rsqrtf(var + 1e-5f);
  float4 g0 = *(const float4*)&g[d],  g1 = *(const float4*)&g[d + 4];
  float4 b0 = *(const float4*)&bb[d], b1 = *(const float4*)&bb[d + 4];
  short8 pk;
  pk[0] = (short)f2b((v0.x - mean) * rstd * g0.x + b0.x);
  pk[1] = (short)f2b((v0.y - mean) * rstd * g0.y + b0.y);
  pk[2] = (short)f2b((v0.z - mean) * rstd * g0.z + b0.z);
  pk[3] = (short)f2b((v0.w - mean) * rstd * g0.w + b0.w);
  pk[4] = (short)f2b((v1.x - mean) * rstd * g1.x + b1.x);
  pk[5] = (short)f2b((v1.y - mean) * rstd * g1.y + b1.y);
  pk[6] = (short)f2b((v1.z - mean) * rstd * g1.z + b1.z);
  pk[7] = (short)f2b((v1.w - mean) * rstd * g1.w + b1.w);
  *(short8*)&o[(size_t)row * 512 + d] = pk;
}

// ---------------- LayerNorm (fp32 in) -> bf16 out ----------------
__global__ __launch_bounds__(256) void k_ln(const float* __restrict__ x, const float* __restrict__ g,
                                            const float* __restrict__ bb, bf16* __restrict__ o) {
  int wid = threadIdx.x >> 6, lane = threadIdx.x & 63;
  int row = blockIdx.x * 4 + wid;
  const float* xr = x + (size_t)row * 512;
  int d = lane * 8;
  float4 v0 = *(const float4*)&xr[d];
  float4 v1 = *(const float4*)&xr[d + 4];
  float s = v0.x + v0.y + v0.z + v0.w + v1.x + v1.y + v1.z + v1.w;
  float q = v0.x*v0.x + v0.y*v0.y + v0.z*v0.z + v0.w*v0.w
          + v1.x*v1.x + v1.y*v1.y + v1.z*v1.z + v1.w*v1.w;
#pragma unroll
  for (int t = 32; t; t >>= 1) { s += __shfl_xor(s, t); q += __shfl_xor(q, t); }
  float mean = s * (1.f / 512.f);
  float var  = q * (1.f / 512.f) - mean * mean;
  float rstd = rsqrtf(var + 1e-5f);
  float4 g0 = *(const float4*)&g[d],  g1 = *(const float4*)&g[d + 4];
  float4 b0 = *(const float4*)&bb[d], b1 = *(const float4*)&bb[d + 4];
  short8 pk;
  pk[0] = (short)f2b((v0.x - mean) * rstd * g0.x + b0.x);
  pk[1] = (short)f2b((v0.y - mean) * rstd * g0.y + b0.y);
  pk[2] = (short)f2b((v0.z - mean) * rstd * g0.z + b0.z);
  pk[3] = (short)f2b((v0.w - mean) * rstd * g0.w + b0.w);
  pk[4] = (short)f2b((v1.x - mean) * rstd * g1.x + b1.x);
  pk[5] = (short)f2b((v1.y - mean) * rstd * g1.y + b1.y);
  pk[6] = (short)f2b((v1.z - mean) * rstd * g1.z + b1.z);
  pk[7] = (short)f2b((v1.w - mean) * rstd * g1.w + b1.w);
  *(short8*)&o[(size_t)row * 512 + d] = pk;
}

// ---------------- m97-structure bf16 MFMA GEMM with LDS-bounce epilogue ----------------
template<int RELU, int RESID, int OUTBF, int HID>
__global__ __launch_bounds__(256) void k_gemm(const bf16* __restrict__ A, const bf16* __restrict__ Wt,
                                              const float* __restrict__ bias, const float* __restrict__ resid,
                                              void* __restrict__ Cout, bf16* __restrict__ hidb,
                                              int K, int ldc) {
  __shared__ __align__(16) float cst[32 * 132];     // aliases Al/Bl during K-loop
  bf16* Al = (bf16*)cst;                            // [128*32]
  bf16* Bl = (bf16*)cst + 4096;                     // [128*32]
  int t = threadIdx.x;
  int lane = t & 63;
  int wid = t >> 6;
  int wr = wid >> 1, wc = wid & 1;
  int trow = blockIdx.y * 128, tcol = blockIdx.x * 128;
  f32x4 acc[4][4] = {};
  const int kh = (lane >> 4) * 8;
  const int rl = lane & 15;
  const int srow = lane >> 2;
  const int scol = (lane & 3) * 8;
  for (int kt = 0; kt < K; kt += 32) {
    __syncthreads();
#pragma unroll
    for (int s = 0; s < 2; ++s) {
      int c = wid * 2 + s;
      int row = c * 16 + srow;
      gload16(A  + (size_t)(trow + row) * K + kt + scol, &Al[c * 512]);
      gload16(Wt + (size_t)(tcol + row) * K + kt + scol, &Bl[c * 512]);
    }
    __syncthreads();
    bf16x8 af[4], bg[4];
#pragma unroll
    for (int m = 0; m < 4; ++m) af[m] = *(const bf16x8*)&Al[(wr * 64 + m * 16 + rl) * 32 + kh];
#pragma unroll
    for (int n = 0; n < 4; ++n) bg[n] = *(const bf16x8*)&Bl[(wc * 64 + n * 16 + rl) * 32 + kh];
#pragma unroll
    for (int m = 0; m < 4; ++m)
#pragma unroll
      for (int n = 0; n < 4; ++n)
        acc[m][n] = __builtin_amdgcn_mfma_f32_16x16x32_bf16(af[m], bg[n], acc[m][n], 0, 0, 0);
  }
  // ---- epilogue: LDS bounce, coalesced stores ----
  const int s   = t >> 3;              // 0..31 staging row
  const int seg = (t & 7) * 16;        // 0..112 col segment
  float bv[16];
#pragma unroll
  for (int q = 0; q < 16; q += 4) *(float4*)&bv[q] = *(const float4*)&bias[tcol + seg + q];
#pragma unroll
  for (int m = 0; m < 4; ++m) {
    __syncthreads();
#pragma unroll
    for (int n = 0; n < 4; ++n) {
      int col = wc * 64 + n * 16 + rl;
#pragma unroll
      for (int j = 0; j < 4; ++j) {
        int sr = wr * 16 + (lane >> 4) * 4 + j;
        cst[sr * 132 + col] = acc[m][n][j];
      }
    }
    __syncthreads();
    int grow = trow + m * 16 + (s < 16 ? s : 48 + s);   // s>=16 -> row block +64
    size_t base = (size_t)grow * ldc + tcol + seg;
    float v[16];
#pragma unroll
    for (int q = 0; q < 16; q += 4) {
      float4 f = *(float4*)&cst[s * 132 + seg + q];
      v[q] = f.x; v[q+1] = f.y; v[q+2] = f.z; v[q+3] = f.w;
    }
    if (RESID) {
#pragma unroll
      for (int q = 0; q < 16; q += 4) {
        float4 r = *(const float4*)&resid[base + q];
        v[q] += r.x; v[q+1] += r.y; v[q+2] += r.z; v[q+3] += r.w;
      }
    }
#pragma unroll
    for (int q = 0; q < 16; ++q) {
      float val = v[q] + bv[q];
      if (RELU) val = fmaxf(val, 0.f);
      v[q] = val;
    }
    if (OUTBF) {
      short8 p0, p1;
#pragma unroll
      for (int q = 0; q < 8; ++q) { p0[q] = (short)f2b(v[q]); p1[q] = (short)f2b(v[8 + q]); }
      *(short8*)&((bf16*)Cout)[base]     = p0;
      *(short8*)&((bf16*)Cout)[base + 8] = p1;
    } else {
#pragma unroll
      for (int q = 0; q < 16; q += 4) {
        float4 o; o.x = v[q]; o.y = v[q+1]; o.z = v[q+2]; o.w = v[q+3];
        *(float4*)&((float*)Cout)[base + q] = o;
      }
      if (HID) {
        short8 p0, p1;
#pragma unroll
        for (int q = 0; q < 8; ++q) { p0[q] = (short)f2b(v[q]); p1[q] = (short)f2b(v[8 + q]); }
        *(short8*)&hidb[base]     = p0;
        *(short8*)&hidb[base + 8] = p1;
      }
    }
  }
}

// ---------------- vp GEMM: A bf16, W fp32 direct (in-register cvt), bf16 logits + partial expsums ----
// gridDim=(8,250), M-fastest + XCD swizzle. B staged f32 via global_load_lds into linear LDS
// with both-sides XOR swizzle (byte ^= (row&7)<<4): source pre-swizzled, read swizzled.
__global__ __launch_bounds__(256) void k_gemm_vp(const bf16* __restrict__ A, const float* __restrict__ Wt,
                                                 const float* __restrict__ bias, bf16* __restrict__ Cout,
                                                 float* __restrict__ partial, int K, int ldc) {
  __shared__ __align__(16) float cst[6144];   // 24 KB: Al bf16 8KB + Bl f32 16KB; epilogue reuses
  bf16*  Al = (bf16*)cst;                     // [128][32] bf16
  float* Bl = cst + 2048;                     // [128][32] f32, XOR-swizzled rows
  int t = threadIdx.x;
  int lane = t & 63;
  int wid = t >> 6;
  int wr = wid >> 1, wc = wid & 1;
  int bid = blockIdx.y * gridDim.x + blockIdx.x;  // (8,250)
  int swz = (bid & 7) * 250 + (bid >> 3);         // XCD k owns contiguous 250 blocks
  int trow = (swz & 7) * 128;
  int ct   = swz >> 3;                            // col tile 0..249
  int tcol = ct * 128;
  f32x4 acc[4][4] = {};
  const int kh = (lane >> 4) * 8;
  const int rl = lane & 15;
  const int srow = lane >> 2;
  const int scol = (lane & 3) * 8;
  for (int kt = 0; kt < K; kt += 32) {
    __syncthreads();
#pragma unroll
    for (int s = 0; s < 2; ++s) {
      int c = wid * 2 + s;
      int row = c * 16 + srow;
      gload16(A + (size_t)(trow + row) * K + kt + scol, &Al[c * 512]);
    }
#pragma unroll
    for (int s = 0; s < 4; ++s) {
      int li  = s * 256 + t;                 // 16B unit within 16KB tile
      int row = li >> 3;                     // 8 x 16B per 128B row
      int cb  = (li & 7) * 16;               // byte col in row
      int sc  = cb ^ ((row & 7) << 4);       // inverse-swizzled SOURCE col
      gload16(Wt + (size_t)(tcol + row) * K + kt + (sc >> 2), &Bl[s * 1024 + wid * 256]);
    }
    __syncthreads();
    bf16x8 af[4], bg[4];
#pragma unroll
    for (int m = 0; m < 4; ++m) af[m] = *(const bf16x8*)&Al[(wr * 64 + m * 16 + rl) * 32 + kh];
#pragma unroll
    for (int n = 0; n < 4; ++n) {
      int row = wc * 64 + n * 16 + rl;
      int rx  = (row & 7) << 4;
      const char* bp = (const char*)(Bl + row * 32);
      float4 x0 = *(const float4*)(bp + ((kh * 4) ^ rx));
      float4 x1 = *(const float4*)(bp + ((kh * 4 + 16) ^ rx));
      short8 tb;
      tb[0] = (short)f2b(x0.x); tb[1] = (short)f2b(x0.y); tb[2] = (short)f2b(x0.z); tb[3] = (short)f2b(x0.w);
      tb[4] = (short)f2b(x1.x); tb[5] = (short)f2b(x1.y); tb[6] = (short)f2b(x1.z); tb[7] = (short)f2b(x1.w);
      bg[n] = __builtin_bit_cast(bf16x8, tb);
    }
#pragma unroll
    for (int m = 0; m < 4; ++m)
#pragma unroll
      for (int n = 0; n < 4; ++n)
        acc[m][n] = __builtin_amdgcn_mfma_f32_16x16x32_bf16(af[m], bg[n], acc[m][n], 0, 0, 0);
  }
  // ---- epilogue: LDS bounce, bf16 logit store + per-(row,ct) expsum partial ----
  const int s   = t >> 3;
  const int seg = (t & 7) * 16;
  float bv[16];
#pragma unroll
  for (int q = 0; q < 16; q += 4) *(float4*)&bv[q] = *(const float4*)&bias[tcol + seg + q];
#pragma unroll
  for (int m = 0; m < 4; ++m) {
    __syncthreads();
#pragma unroll
    for (int n = 0; n < 4; ++n) {
      int col = wc * 64 + n * 16 + rl;
#pragma unroll
      for (int j = 0; j < 4; ++j)
        cst[(wr * 16 + (lane >> 4) * 4 + j) * 132 + col] = acc[m][n][j];
    }
    __syncthreads();
    int grow = trow + m * 16 + (s < 16 ? s : 48 + s);
    size_t base = (size_t)grow * ldc + tcol + seg;
    float v[16];
#pragma unroll
    for (int q = 0; q < 16; q += 4) {
      float4 f = *(float4*)&cst[s * 132 + seg + q];
      v[q] = f.x; v[q+1] = f.y; v[q+2] = f.z; v[q+3] = f.w;
    }
    short8 p0, p1;
    float e = 0.f;
#pragma unroll
    for (int q = 0; q < 8; ++q) {
      unsigned short u0 = f2b(v[q] + bv[q]);
      unsigned short u1 = f2b(v[8 + q] + bv[8 + q]);
      p0[q] = (short)u0; p1[q] = (short)u1;
      e += __expf(b2f(u0)) + __expf(b2f(u1));
    }
    *(short8*)&Cout[base]     = p0;
    *(short8*)&Cout[base + 8] = p1;
    e += __shfl_xor(e, 1); e += __shfl_xor(e, 2); e += __shfl_xor(e, 4);
    if ((t & 7) == 0) partial[(size_t)grow * 256 + ct] = e;
  }
}

// ---------------- attention (fp32 math): one block per (b,h), 32 q-rows per block ----------------
template<int MASK, int WPROB>
__global__ __launch_bounds__(256) void k_attn(const float* __restrict__ Qb, int qs,
                                              const float* __restrict__ Kb, int ks,
                                              const float* __restrict__ Vb, int vs,
                                              float* __restrict__ probs, bf16* __restrict__ Ob, int os) {
  __shared__ float KV[128][68];
  __shared__ float Sc[32][132];
  int t = threadIdx.x;
  int bh = blockIdx.x; int b = bh >> 3, h = bh & 7;
  int rb = blockIdx.y * 32;
  int r = t >> 3, sub = t & 7;
  const float* Kp = Kb + (size_t)(b * 128) * ks + h * 64;
  const float* Vp = Vb + (size_t)(b * 128) * vs + h * 64;
  const float* Qp = Qb + (size_t)(b * 128 + rb + r) * qs + h * 64;
  float4 q[16];
#pragma unroll
  for (int i = 0; i < 16; ++i) q[i] = *(const float4*)&Qp[i * 4];
  for (int i = 0; i < 32; ++i) { int u = t + i * 256; int rr = u >> 6, dd = u & 63; KV[rr][dd] = Kp[(size_t)rr * ks + dd]; }
  __syncthreads();
  float sc[16];
#pragma unroll
  for (int i = 0; i < 16; ++i) {
    int c = sub + i * 8;
    float a = 0.f;
#pragma unroll
    for (int d4 = 0; d4 < 16; ++d4) {
      float4 k4 = *(const float4*)&KV[c][d4 * 4];
      a += q[d4].x * k4.x + q[d4].y * k4.y + q[d4].z * k4.z + q[d4].w * k4.w;
    }
    a *= 0.125f;
    if (MASK && c > rb + r) a -= 1e9f;
    sc[i] = a;
  }
  float mx = -1e30f;
#pragma unroll
  for (int i = 0; i < 16; ++i) mx = fmaxf(mx, sc[i]);
  mx = fmaxf(mx, __shfl_xor(mx, 1)); mx = fmaxf(mx, __shfl_xor(mx, 2)); mx = fmaxf(mx, __shfl_xor(mx, 4));
  float sm = 0.f;
#pragma unroll
  for (int i = 0; i < 16; ++i) { sc[i] = __expf(sc[i] - mx); sm += sc[i]; }
  sm += __shfl_xor(sm, 1); sm += __shfl_xor(sm, 2); sm += __shfl_xor(sm, 4);
  float inv = 1.f / sm;
#pragma unroll
  for (int i = 0; i < 16; ++i) {
    float p = sc[i] * inv;
    Sc[r][sub + i * 8] = p;
    if (WPROB) probs[(((size_t)(b * 8 + h) * 128) + rb + r) * 128 + sub + i * 8] = p;
  }
  __syncthreads();
  for (int i = 0; i < 32; ++i) { int u = t + i * 256; int rr = u >> 6, dd = u & 63; KV[rr][dd] = Vp[(size_t)rr * vs + dd]; }
  __syncthreads();
  int dg = sub;
  float4 o0 = {0,0,0,0}, o1 = {0,0,0,0};
  for (int j = 0; j < 128; ++j) {
    float p = Sc[r][j];
    float4 va = *(const float4*)&KV[j][dg * 8];
    float4 vb = *(const float4*)&KV[j][dg * 8 + 4];
    o0.x += p * va.x; o0.y += p * va.y; o0.z += p * va.z; o0.w += p * va.w;
    o1.x += p * vb.x; o1.y += p * vb.y; o1.z += p * vb.z; o1.w += p * vb.w;
  }
  short8 pk;
  pk[0] = (short)f2b(o0.x); pk[1] = (short)f2b(o0.y); pk[2] = (short)f2b(o0.z); pk[3] = (short)f2b(o0.w);
  pk[4] = (short)f2b(o1.x); pk[5] = (short)f2b(o1.y); pk[6] = (short)f2b(o1.z); pk[7] = (short)f2b(o1.w);
  *(short8*)&Ob[(size_t)(b * 128 + rb + r) * os + h * 64 + dg * 8] = pk;
}

// ---------------- fused: attn mean over heads + aavg out + ctx = aavg @ emofused ----------------
__global__ __launch_bounds__(256) void k_ctx2(const float* __restrict__ abuf, const float* __restrict__ emo,
                                              float* __restrict__ aavg, float* __restrict__ ctx) {
  __shared__ float aw[8][132];
  int b = blockIdx.x, rb = blockIdx.y * 8;
  int t = threadIdx.x;
  for (int i = t; i < 1024; i += 256) {
    int r = i >> 7, l = i & 127;
    float s = 0.f;
#pragma unroll
    for (int h = 0; h < 8; ++h) s += abuf[(((size_t)(b * 8 + h) * 128) + rb + r) * 128 + l];
    s *= 0.125f;
    aw[r][l] = s;
    aavg[(size_t)(b * 128 + rb + r) * 128 + l] = s;
  }
  __syncthreads();
  int d = t * 2;
  float2 acc[8] = {};
  for (int l = 0; l < 128; ++l) {
    float2 e = *(const float2*)&emo[(size_t)(b * 128 + l) * 512 + d];
#pragma unroll
    for (int r = 0; r < 8; ++r) { acc[r].x += aw[r][l] * e.x; acc[r].y += aw[r][l] * e.y; }
  }
#pragma unroll
  for (int r = 0; r < 8; ++r) *(float2*)&ctx[(size_t)(b * 128 + rb + r) * 512 + d] = acc[r];
}

// ---------------- fused: p_mix gate + partial-reduce rowsum + single-pass finalize ----------------
__global__ __launch_bounds__(256) void k_softmax_final(
    const bf16* __restrict__ lg, const float* __restrict__ partial,
    const float* __restrict__ hid, const float* __restrict__ ctx, const float* __restrict__ emb,
    const float* __restrict__ pgw, const float* __restrict__ pgb,
    float* __restrict__ pmix_out, float* __restrict__ pgen, float* __restrict__ pw,
    float* __restrict__ pcopy) {
  __shared__ float red[8];
  int row = blockIdx.x;
  int t = threadIdx.x, lane = t & 63, wid = t >> 6;
  // gate dot partial
  float s;
  {
    int d = t * 2;
    float2 h2 = *(const float2*)&hid[(size_t)row * 512 + d];
    float2 c2 = *(const float2*)&ctx[(size_t)row * 512 + d];
    float2 e2 = *(const float2*)&emb[(size_t)row * 512 + d];
    float2 g0 = *(const float2*)&pgw[d];
    float2 g1 = *(const float2*)&pgw[512 + d];
    float2 g2 = *(const float2*)&pgw[1024 + d];
    s = h2.x*g0.x + h2.y*g0.y + c2.x*g1.x + c2.y*g1.y + e2.x*g2.x + e2.y*g2.y;
  }
  // rowsum partial (250 col-tile contributions)
  float rs = (t < 250) ? partial[(size_t)row * 256 + t] : 0.f;
#pragma unroll
  for (int o = 32; o; o >>= 1) { s += __shfl_xor(s, o); rs += __shfl_xor(rs, o); }
  if (lane == 0) { red[wid] = s; red[4 + wid] = rs; }
  __syncthreads();
  s  = red[0] + red[1] + red[2] + red[3];
  rs = red[4] + red[5] + red[6] + red[7];
  float pm = 1.f / (1.f + __expf(-(s + pgb[0])));
  if (t == 0) pmix_out[row] = pm;
  float inv = 1.f / rs;
  const bf16* L = lg + (size_t)row * 32000;
  float* pgen_r  = pgen  + (size_t)row * 32100;
  float* pw_r    = pw    + (size_t)row * 32100;
  float* pcopy_r = pcopy + (size_t)row * 32100;
  float4 z = {0.f, 0.f, 0.f, 0.f};
  for (int i = t; i < 4000; i += 256) {
    short8 v = *(const short8*)(L + i * 8);
    float p[8];
#pragma unroll
    for (int c = 0; c < 8; ++c) p[c] = __expf(b2f((unsigned short)v[c])) * inv;
    float4 a0 = {p[0], p[1], p[2], p[3]};
    float4 a1 = {p[4], p[5], p[6], p[7]};
    *(float4*)&pgen_r[i * 8]     = a0;
    *(float4*)&pgen_r[i * 8 + 4] = a1;
    float4 w0 = {pm * p[0], pm * p[1], pm * p[2], pm * p[3]};
    float4 w1 = {pm * p[4], pm * p[5], pm * p[6], pm * p[7]};
    *(float4*)&pw_r[i * 8]     = w0;
    *(float4*)&pw_r[i * 8 + 4] = w1;
    *(float4*)&pcopy_r[i * 8]     = z;
    *(float4*)&pcopy_r[i * 8 + 4] = z;
  }
  if (t < 25) {   // pad cols 32000..32099
    int c = 32000 + t * 4;
    *(float4*)&pgen_r[c] = z; *(float4*)&pw_r[c] = z; *(float4*)&pcopy_r[c] = z;
  }
}

// ---------------- scatter copy-distribution (separate dispatch after finalize) ----------------
__global__ __launch_bounds__(256) void k_scatter(const int* __restrict__ src, const float* __restrict__ aavg,
                                                 const float* __restrict__ pmix, float* __restrict__ pw,
                                                 float* __restrict__ pcopy) {
  int tid = blockIdx.x * 256 + threadIdx.x;   // 16384
  int row = tid >> 4, slot = tid & 15;
  int b = row >> 7;
  float qg = 1.f - pmix[row];
#pragma unroll
  for (int i = 0; i < 8; ++i) {
    int l = slot * 8 + i;
    int c = src[b * 128 + l];
    float w = aavg[(size_t)row * 128 + l];
    atomicAdd(&pcopy[(size_t)row * 32100 + c], w);
    atomicAdd(&pw[(size_t)row * 32100 + c], qg * w);
  }
}

// ================= host launch =================
extern "C" void kernel_launch(void* const* d_in, const int* in_sizes, int n_in,
                              void* d_out, int out_size, void* d_ws, size_t ws_size,
                              hipStream_t stream) {
  const int*   ids      = (const int*)d_in[0];
  const float* emo      = (const float*)d_in[1];
  const int*   src      = (const int*)d_in[2];
  const float* tok      = (const float*)d_in[4];
  const float* pos      = (const float*)d_in[5];
  const float* sa_in_w  = (const float*)d_in[6];
  const float* sa_in_b  = (const float*)d_in[7];
  const float* sa_out_w = (const float*)d_in[8];
  const float* sa_out_b = (const float*)d_in[9];
  const float* ca_in_w  = (const float*)d_in[10];
  const float* ca_in_b  = (const float*)d_in[11];
  const float* ca_out_w = (const float*)d_in[12];
  const float* ca_out_b = (const float*)d_in[13];
  const float* w1       = (const float*)d_in[14];
  const float* b1       = (const float*)d_in[15];
  const float* w2       = (const float*)d_in[16];
  const float* b2       = (const float*)d_in[17];
  const float* n1g      = (const float*)d_in[18];
  const float* n1b      = (const float*)d_in[19];
  const float* n2g      = (const float*)d_in[20];
  const float* n2b      = (const float*)d_in[21];
  const float* n3g      = (const float*)d_in[22];
  const float* n3b      = (const float*)d_in[23];
  const float* vpw      = (const float*)d_in[24];
  const float* vpb      = (const float*)d_in[25];
  const float* pgw      = (const float*)d_in[26];
  const float* pgb      = (const float*)d_in[27];
  (void)in_sizes; (void)n_in; (void)out_size; (void)ws_size;

  // output regions (floats)
  constexpr size_t NR = 1024;
  float* out     = (float*)d_out;
  float* o_pw    = out;
  float* o_pgen  = out + NR * 32100;
  float* o_pcopy = out + 2 * NR * 32100;
  float* o_pmix  = out + 3 * NR * 32100;
  float* o_hid   = o_pmix + NR;
  float* o_aavg  = o_hid + NR * 512;
  float* o_ctx   = o_aavg + NR * 128;

  // workspace layout
  char* wp = (char*)d_ws;
  size_t off = 0;
  auto alloc = [&](size_t bytes) { char* r = wp + off; off += (bytes + 255) & ~(size_t)255; return r; };
  bf16*  sa_in_bf  = (bf16*)alloc(3 * 512 * 512 * 2);
  bf16*  sa_out_bf = (bf16*)alloc(512 * 512 * 2);
  bf16*  ca_in_bf  = (bf16*)alloc(3 * 512 * 512 * 2);
  bf16*  ca_out_bf = (bf16*)alloc(512 * 512 * 2);
  bf16*  w1_bf     = (bf16*)alloc(2048 * 512 * 2);
  bf16*  w2_bf     = (bf16*)alloc(2048 * 512 * 2);
  bf16*  emo_bf    = (bf16*)alloc(8 * 128 * 512 * 2);
  float* x         = (float*)alloc(1024 * 512 * 4);
  float* embf      = (float*)alloc(1024 * 512 * 4);
  bf16*  hbf       = (bf16*)alloc(1024 * 512 * 2);
  float* qkv       = (float*)alloc(1024 * 1536 * 4);
  bf16*  aout_bf   = (bf16*)alloc(1024 * 512 * 2);
  float* qca       = (float*)alloc(1024 * 512 * 4);
  float* kvca      = (float*)alloc(1024 * 1024 * 4);
  float* abuf      = (float*)alloc((size_t)8 * 8 * 128 * 128 * 4);
  bf16*  f1bf      = (bf16*)alloc(1024 * 2048 * 2);
  bf16*  hid_bf    = (bf16*)alloc(1024 * 512 * 2);
  bf16*  logits_bf = (bf16*)alloc((size_t)1024 * 32000 * 2);
  float* partial   = (float*)alloc((size_t)1024 * 256 * 4);

  // 1. small-weight casts
  k_cast_all<<<2048, 256, 0, stream>>>(sa_in_w, sa_in_bf, sa_out_w, sa_out_bf,
                                       ca_in_w, ca_in_bf, ca_out_w, ca_out_bf,
                                       w1, w1_bf, w2, w2_bf, emo, emo_bf);

  // 2. embedding + LN1 (fused)
  k_embed_ln<<<256, 256, 0, stream>>>(ids, tok, pos, n1g, n1b, x, embf, hbf);

  // 3-5. self-attention block
  k_gemm<0,0,0,0><<<dim3(12, 8), 256, 0, stream>>>(hbf, sa_in_bf, sa_in_b, nullptr, qkv, nullptr, 512, 1536);
  k_attn<1,0><<<dim3(64, 4), 256, 0, stream>>>(qkv, 1536, qkv + 512, 1536, qkv + 1024, 1536,
                                               nullptr, aout_bf, 512);
  k_gemm<0,1,0,0><<<dim3(4, 8), 256, 0, stream>>>(aout_bf, sa_out_bf, sa_out_b, x, x, nullptr, 512, 512);

  // 6-11. cross-attention block
  k_ln<<<256, 256, 0, stream>>>(x, n2g, n2b, hbf);
  k_gemm<0,0,0,0><<<dim3(4, 8), 256, 0, stream>>>(hbf, ca_in_bf, ca_in_b, nullptr, qca, nullptr, 512, 512);
  k_gemm<0,0,0,0><<<dim3(8, 8), 256, 0, stream>>>(emo_bf, ca_in_bf + 512 * 512, ca_in_b + 512,
                                                  nullptr, kvca, nullptr, 512, 1024);
  k_attn<0,1><<<dim3(64, 4), 256, 0, stream>>>(qca, 512, kvca, 1024, kvca + 512, 1024,
                                               abuf, aout_bf, 512);
  k_ctx2<<<dim3(8, 16), 256, 0, stream>>>(abuf, emo, o_aavg, o_ctx);
  k_gemm<0,1,0,0><<<dim3(4, 8), 256, 0, stream>>>(aout_bf, ca_out_bf, ca_out_b, x, x, nullptr, 512, 512);

  // 12-14. FFN (ffn2 fused with hidden fp32+bf16 output)
  k_ln<<<256, 256, 0, stream>>>(x, n3g, n3b, hbf);
  k_gemm<1,0,1,0><<<dim3(16, 8), 256, 0, stream>>>(hbf, w1_bf, b1, nullptr, f1bf, nullptr, 512, 2048);
  k_gemm<0,1,0,1><<<dim3(4, 8), 256, 0, stream>>>(f1bf, w2_bf, b2, x, o_hid, hid_bf, 2048, 512);

  // 15. vocab projection: fp32 W direct, bf16 logits + per-tile expsum partials
  k_gemm_vp<<<dim3(8, 250), 256, 0, stream>>>(hid_bf, vpw, vpb, logits_bf, partial, 512, 32000);

  // 16. gate + rowsum reduce + single-pass finalize
  k_softmax_final<<<1024, 256, 0, stream>>>(logits_bf, partial, o_hid, o_ctx, embf, pgw, pgb,
                                            o_pmix, o_pgen, o_pw, o_pcopy);

  // 17. scatter
  k_scatter<<<64, 256, 0, stream>>>(src, o_aavg, o_pmix, o_pw, o_pcopy);
}

// Round 9
// 453.523 us; speedup vs baseline: 1.0350x; 1.0350x over previous
//
#include <hip/hip_runtime.h>
#include <hip/hip_bf16.h>

using bf16   = __hip_bfloat16;
using bf16x8 = __attribute__((ext_vector_type(8))) __bf16;
using f32x4  = __attribute__((ext_vector_type(4))) float;
using short8 = __attribute__((ext_vector_type(8))) short;

__device__ __forceinline__ unsigned short f2b(float x) {
  union { bf16 b; unsigned short u; } t; t.b = __float2bfloat16(x); return t.u;
}
__device__ __forceinline__ float b2f(unsigned short u) {
  union { unsigned int i; float f; } t; t.i = ((unsigned int)u) << 16; return t.f;
}

typedef __attribute__((address_space(1))) const unsigned int* gas1_t;
typedef __attribute__((address_space(3))) unsigned int* las3_t;
__device__ __forceinline__ void gload16(const void* g, void* l) {
  __builtin_amdgcn_global_load_lds((gas1_t)g, (las3_t)l, 16, 0, 0);
}

// ---------------- all f32->bf16 casts in one grid-stride kernel ----------------
__global__ __launch_bounds__(256) void k_cast_all(
    const float* __restrict__ vpsrc, bf16* __restrict__ vpdst,      // 4096000 f4
    const float* __restrict__ s0, bf16* __restrict__ d0,            // sa_in 196608
    const float* __restrict__ s1, bf16* __restrict__ d1,            // sa_out 65536
    const float* __restrict__ s2, bf16* __restrict__ d2,            // ca_in 196608
    const float* __restrict__ s3, bf16* __restrict__ d3,            // ca_out 65536
    const float* __restrict__ s4, bf16* __restrict__ d4,            // w1 262144
    const float* __restrict__ s5, bf16* __restrict__ d5,            // w2 262144
    const float* __restrict__ s6, bf16* __restrict__ d6) {          // emo 131072
  int i = blockIdx.x * 256 + threadIdx.x;
  int str = gridDim.x * 256;
  for (; i < 5275648; i += str) {
    if (i < 4096000) {
      float4 v = ((const float4*)vpsrc)[i];
      ushort4 u; u.x = f2b(v.x); u.y = f2b(v.y); u.z = f2b(v.z); u.w = f2b(v.w);
      ((ushort4*)vpdst)[i] = u;
    } else {
      int j = i - 4096000;
      const float* s; bf16* d; int off;
      if      (j <  196608) { s = s0; d = d0; off = j; }
      else if (j <  262144) { s = s1; d = d1; off = j - 196608; }
      else if (j <  458752) { s = s2; d = d2; off = j - 262144; }
      else if (j <  524288) { s = s3; d = d3; off = j - 458752; }
      else if (j <  786432) { s = s4; d = d4; off = j - 524288; }
      else if (j < 1048576) { s = s5; d = d5; off = j - 786432; }
      else                  { s = s6; d = d6; off = j - 1048576; }
      float4 v = ((const float4*)s)[off];
      ushort4 u; u.x = f2b(v.x); u.y = f2b(v.y); u.z = f2b(v.z); u.w = f2b(v.w);
      ((ushort4*)d)[off] = u;
    }
  }
}

// ---------------- fused token+pos embedding + LayerNorm1 ----------------
__global__ __launch_bounds__(256) void k_embed_ln(const int* __restrict__ ids, const float* __restrict__ tok,
                                                  const float* __restrict__ pos, const float* __restrict__ g,
                                                  const float* __restrict__ bb, float* __restrict__ x,
                                                  float* __restrict__ emb, bf16* __restrict__ o) {
  int wid = threadIdx.x >> 6, lane = threadIdx.x & 63;
  int row = blockIdx.x * 4 + wid;
  int tt = row & 127;
  int id = ids[row];
  int d = lane * 8;
  float4 e0 = *(const float4*)&tok[(size_t)id * 512 + d];
  float4 e1 = *(const float4*)&tok[(size_t)id * 512 + d + 4];
  float4 p0 = *(const float4*)&pos[(size_t)tt * 512 + d];
  float4 p1 = *(const float4*)&pos[(size_t)tt * 512 + d + 4];
  *(float4*)&emb[(size_t)row * 512 + d]     = e0;
  *(float4*)&emb[(size_t)row * 512 + d + 4] = e1;
  float4 v0; v0.x = e0.x + p0.x; v0.y = e0.y + p0.y; v0.z = e0.z + p0.z; v0.w = e0.w + p0.w;
  float4 v1; v1.x = e1.x + p1.x; v1.y = e1.y + p1.y; v1.z = e1.z + p1.z; v1.w = e1.w + p1.w;
  *(float4*)&x[(size_t)row * 512 + d]     = v0;
  *(float4*)&x[(size_t)row * 512 + d + 4] = v1;
  float s = v0.x + v0.y + v0.z + v0.w + v1.x + v1.y + v1.z + v1.w;
  float q = v0.x*v0.x + v0.y*v0.y + v0.z*v0.z + v0.w*v0.w
          + v1.x*v1.x + v1.y*v1.y + v1.z*v1.z + v1.w*v1.w;
#pragma unroll
  for (int t = 32; t; t >>= 1) { s += __shfl_xor(s, t); q += __shfl_xor(q, t); }
  float mean = s * (1.f / 512.f);
  float var  = q * (1.f / 512.f) - mean * mean;
  float rstd = rsqrtf(var + 1e-5f);
  float4 g0 = *(const float4*)&g[d],  g1 = *(const float4*)&g[d + 4];
  float4 b0 = *(const float4*)&bb[d], b1 = *(const float4*)&bb[d + 4];
  short8 pk;
  pk[0] = (short)f2b((v0.x - mean) * rstd * g0.x + b0.x);
  pk[1] = (short)f2b((v0.y - mean) * rstd * g0.y + b0.y);
  pk[2] = (short)f2b((v0.z - mean) * rstd * g0.z + b0.z);
  pk[3] = (short)f2b((v0.w - mean) * rstd * g0.w + b0.w);
  pk[4] = (short)f2b((v1.x - mean) * rstd * g1.x + b1.x);
  pk[5] = (short)f2b((v1.y - mean) * rstd * g1.y + b1.y);
  pk[6] = (short)f2b((v1.z - mean) * rstd * g1.z + b1.z);
  pk[7] = (short)f2b((v1.w - mean) * rstd * g1.w + b1.w);
  *(short8*)&o[(size_t)row * 512 + d] = pk;
}

// ---------------- LayerNorm (fp32 in) -> bf16 out ----------------
__global__ __launch_bounds__(256) void k_ln(const float* __restrict__ x, const float* __restrict__ g,
                                            const float* __restrict__ bb, bf16* __restrict__ o) {
  int wid = threadIdx.x >> 6, lane = threadIdx.x & 63;
  int row = blockIdx.x * 4 + wid;
  const float* xr = x + (size_t)row * 512;
  int d = lane * 8;
  float4 v0 = *(const float4*)&xr[d];
  float4 v1 = *(const float4*)&xr[d + 4];
  float s = v0.x + v0.y + v0.z + v0.w + v1.x + v1.y + v1.z + v1.w;
  float q = v0.x*v0.x + v0.y*v0.y + v0.z*v0.z + v0.w*v0.w
          + v1.x*v1.x + v1.y*v1.y + v1.z*v1.z + v1.w*v1.w;
#pragma unroll
  for (int t = 32; t; t >>= 1) { s += __shfl_xor(s, t); q += __shfl_xor(q, t); }
  float mean = s * (1.f / 512.f);
  float var  = q * (1.f / 512.f) - mean * mean;
  float rstd = rsqrtf(var + 1e-5f);
  float4 g0 = *(const float4*)&g[d],  g1 = *(const float4*)&g[d + 4];
  float4 b0 = *(const float4*)&bb[d], b1 = *(const float4*)&bb[d + 4];
  short8 pk;
  pk[0] = (short)f2b((v0.x - mean) * rstd * g0.x + b0.x);
  pk[1] = (short)f2b((v0.y - mean) * rstd * g0.y + b0.y);
  pk[2] = (short)f2b((v0.z - mean) * rstd * g0.z + b0.z);
  pk[3] = (short)f2b((v0.w - mean) * rstd * g0.w + b0.w);
  pk[4] = (short)f2b((v1.x - mean) * rstd * g1.x + b1.x);
  pk[5] = (short)f2b((v1.y - mean) * rstd * g1.y + b1.y);
  pk[6] = (short)f2b((v1.z - mean) * rstd * g1.z + b1.z);
  pk[7] = (short)f2b((v1.w - mean) * rstd * g1.w + b1.w);
  *(short8*)&o[(size_t)row * 512 + d] = pk;
}

// ---------------- m97-structure bf16 MFMA GEMM with LDS-bounce epilogue ----------------
// SWZ: vp grid mapping (gridDim=(8,250), M-fastest + XCD swizzle).
// HID: also write bf16 copy of fp32 output.
// EXPS: per-(row, col-tile) partial expsum of bf16 logits -> partial[row*256+ct] (no atomics).
template<int RELU, int RESID, int OUTBF, int SWZ, int HID, int EXPS>
__global__ __launch_bounds__(256) void k_gemm(const bf16* __restrict__ A, const bf16* __restrict__ Wt,
                                              const float* __restrict__ bias, const float* __restrict__ resid,
                                              void* __restrict__ Cout, bf16* __restrict__ hidb,
                                              float* __restrict__ partial, int K, int ldc) {
  __shared__ __align__(16) float cst[32 * 132];     // 16896 B; aliases Al/Bl during K-loop
  bf16* Al = (bf16*)cst;                            // [128*32]
  bf16* Bl = (bf16*)cst + 4096;                     // [128*32]
  int t = threadIdx.x;
  int lane = t & 63;
  int wid = t >> 6;
  int wr = wid >> 1, wc = wid & 1;
  int trow, tcol;
  if (SWZ) {
    int bid = blockIdx.y * gridDim.x + blockIdx.x;  // gridDim=(8,250)
    int swz = (bid & 7) * 250 + (bid >> 3);         // XCD k owns a contiguous 250-block chunk
    trow = (swz & 7) * 128;
    tcol = (swz >> 3) * 128;
  } else {
    trow = blockIdx.y * 128; tcol = blockIdx.x * 128;
  }
  f32x4 acc[4][4] = {};
  const int kh = (lane >> 4) * 8;
  const int rl = lane & 15;
  const int srow = lane >> 2;
  const int scol = (lane & 3) * 8;
  for (int kt = 0; kt < K; kt += 32) {
    __syncthreads();
#pragma unroll
    for (int s = 0; s < 2; ++s) {
      int c = wid * 2 + s;
      int row = c * 16 + srow;
      gload16(A  + (size_t)(trow + row) * K + kt + scol, &Al[c * 512]);
      gload16(Wt + (size_t)(tcol + row) * K + kt + scol, &Bl[c * 512]);
    }
    __syncthreads();
    bf16x8 af[4], bg[4];
#pragma unroll
    for (int m = 0; m < 4; ++m) af[m] = *(const bf16x8*)&Al[(wr * 64 + m * 16 + rl) * 32 + kh];
#pragma unroll
    for (int n = 0; n < 4; ++n) bg[n] = *(const bf16x8*)&Bl[(wc * 64 + n * 16 + rl) * 32 + kh];
#pragma unroll
    for (int m = 0; m < 4; ++m)
#pragma unroll
      for (int n = 0; n < 4; ++n)
        acc[m][n] = __builtin_amdgcn_mfma_f32_16x16x32_bf16(af[m], bg[n], acc[m][n], 0, 0, 0);
  }
  // ---- epilogue: LDS bounce, coalesced stores ----
  const int s   = t >> 3;              // 0..31 staging row
  const int seg = (t & 7) * 16;        // 0..112 col segment
  float bv[16];
#pragma unroll
  for (int q = 0; q < 16; q += 4) *(float4*)&bv[q] = *(const float4*)&bias[tcol + seg + q];
#pragma unroll
  for (int m = 0; m < 4; ++m) {
    __syncthreads();
#pragma unroll
    for (int n = 0; n < 4; ++n) {
      int col = wc * 64 + n * 16 + rl;
#pragma unroll
      for (int j = 0; j < 4; ++j) {
        int sr = wr * 16 + (lane >> 4) * 4 + j;
        cst[sr * 132 + col] = acc[m][n][j];
      }
    }
    __syncthreads();
    int grow = trow + m * 16 + (s < 16 ? s : 48 + s);   // s>=16 -> row block +64
    size_t base = (size_t)grow * ldc + tcol + seg;
    float v[16];
#pragma unroll
    for (int q = 0; q < 16; q += 4) {
      float4 f = *(float4*)&cst[s * 132 + seg + q];
      v[q] = f.x; v[q+1] = f.y; v[q+2] = f.z; v[q+3] = f.w;
    }
    if (RESID) {
#pragma unroll
      for (int q = 0; q < 16; q += 4) {
        float4 r = *(const float4*)&resid[base + q];
        v[q] += r.x; v[q+1] += r.y; v[q+2] += r.z; v[q+3] += r.w;
      }
    }
#pragma unroll
    for (int q = 0; q < 16; ++q) {
      float val = v[q] + bv[q];
      if (RELU) val = fmaxf(val, 0.f);
      v[q] = val;
    }
    if (OUTBF) {
      short8 p0, p1;
#pragma unroll
      for (int q = 0; q < 8; ++q) { p0[q] = (short)f2b(v[q]); p1[q] = (short)f2b(v[8 + q]); }
      *(short8*)&((bf16*)Cout)[base]     = p0;
      *(short8*)&((bf16*)Cout)[base + 8] = p1;
      if (EXPS) {
        float e = 0.f;
#pragma unroll
        for (int q = 0; q < 8; ++q)
          e += __expf(b2f((unsigned short)p0[q])) + __expf(b2f((unsigned short)p1[q]));
        e += __shfl_xor(e, 1); e += __shfl_xor(e, 2); e += __shfl_xor(e, 4);
        if ((t & 7) == 0) partial[(size_t)grow * 256 + (tcol >> 7)] = e;
      }
    } else {
#pragma unroll
      for (int q = 0; q < 16; q += 4) {
        float4 o; o.x = v[q]; o.y = v[q+1]; o.z = v[q+2]; o.w = v[q+3];
        *(float4*)&((float*)Cout)[base + q] = o;
      }
      if (HID) {
        short8 p0, p1;
#pragma unroll
        for (int q = 0; q < 8; ++q) { p0[q] = (short)f2b(v[q]); p1[q] = (short)f2b(v[8 + q]); }
        *(short8*)&hidb[base]     = p0;
        *(short8*)&hidb[base + 8] = p1;
      }
    }
  }
}

// ---------------- attention (fp32 math): one block per (b,h), 32 q-rows per block ----------------
template<int MASK, int WPROB>
__global__ __launch_bounds__(256) void k_attn(const float* __restrict__ Qb, int qs,
                                              const float* __restrict__ Kb, int ks,
                                              const float* __restrict__ Vb, int vs,
                                              float* __restrict__ probs, bf16* __restrict__ Ob, int os) {
  __shared__ float KV[128][68];
  __shared__ float Sc[32][132];
  int t = threadIdx.x;
  int bh = blockIdx.x; int b = bh >> 3, h = bh & 7;
  int rb = blockIdx.y * 32;
  int r = t >> 3, sub = t & 7;
  const float* Kp = Kb + (size_t)(b * 128) * ks + h * 64;
  const float* Vp = Vb + (size_t)(b * 128) * vs + h * 64;
  const float* Qp = Qb + (size_t)(b * 128 + rb + r) * qs + h * 64;
  float4 q[16];
#pragma unroll
  for (int i = 0; i < 16; ++i) q[i] = *(const float4*)&Qp[i * 4];
  for (int i = 0; i < 32; ++i) { int u = t + i * 256; int rr = u >> 6, dd = u & 63; KV[rr][dd] = Kp[(size_t)rr * ks + dd]; }
  __syncthreads();
  float sc[16];
#pragma unroll
  for (int i = 0; i < 16; ++i) {
    int c = sub + i * 8;
    float a = 0.f;
#pragma unroll
    for (int d4 = 0; d4 < 16; ++d4) {
      float4 k4 = *(const float4*)&KV[c][d4 * 4];
      a += q[d4].x * k4.x + q[d4].y * k4.y + q[d4].z * k4.z + q[d4].w * k4.w;
    }
    a *= 0.125f;
    if (MASK && c > rb + r) a -= 1e9f;
    sc[i] = a;
  }
  float mx = -1e30f;
#pragma unroll
  for (int i = 0; i < 16; ++i) mx = fmaxf(mx, sc[i]);
  mx = fmaxf(mx, __shfl_xor(mx, 1)); mx = fmaxf(mx, __shfl_xor(mx, 2)); mx = fmaxf(mx, __shfl_xor(mx, 4));
  float sm = 0.f;
#pragma unroll
  for (int i = 0; i < 16; ++i) { sc[i] = __expf(sc[i] - mx); sm += sc[i]; }
  sm += __shfl_xor(sm, 1); sm += __shfl_xor(sm, 2); sm += __shfl_xor(sm, 4);
  float inv = 1.f / sm;
#pragma unroll
  for (int i = 0; i < 16; ++i) {
    float p = sc[i] * inv;
    Sc[r][sub + i * 8] = p;
    if (WPROB) probs[(((size_t)(b * 8 + h) * 128) + rb + r) * 128 + sub + i * 8] = p;
  }
  __syncthreads();
  for (int i = 0; i < 32; ++i) { int u = t + i * 256; int rr = u >> 6, dd = u & 63; KV[rr][dd] = Vp[(size_t)rr * vs + dd]; }
  __syncthreads();
  int dg = sub;
  float4 o0 = {0,0,0,0}, o1 = {0,0,0,0};
  for (int j = 0; j < 128; ++j) {
    float p = Sc[r][j];
    float4 va = *(const float4*)&KV[j][dg * 8];
    float4 vb = *(const float4*)&KV[j][dg * 8 + 4];
    o0.x += p * va.x; o0.y += p * va.y; o0.z += p * va.z; o0.w += p * va.w;
    o1.x += p * vb.x; o1.y += p * vb.y; o1.z += p * vb.z; o1.w += p * vb.w;
  }
  short8 pk;
  pk[0] = (short)f2b(o0.x); pk[1] = (short)f2b(o0.y); pk[2] = (short)f2b(o0.z); pk[3] = (short)f2b(o0.w);
  pk[4] = (short)f2b(o1.x); pk[5] = (short)f2b(o1.y); pk[6] = (short)f2b(o1.z); pk[7] = (short)f2b(o1.w);
  *(short8*)&Ob[(size_t)(b * 128 + rb + r) * os + h * 64 + dg * 8] = pk;
}

// ---------------- fused: attn mean over heads + aavg out + ctx = aavg @ emofused ----------------
__global__ __launch_bounds__(256) void k_ctx2(const float* __restrict__ abuf, const float* __restrict__ emo,
                                              float* __restrict__ aavg, float* __restrict__ ctx) {
  __shared__ float aw[8][132];
  int b = blockIdx.x, rb = blockIdx.y * 8;
  int t = threadIdx.x;
  for (int i = t; i < 1024; i += 256) {
    int r = i >> 7, l = i & 127;
    float s = 0.f;
#pragma unroll
    for (int h = 0; h < 8; ++h) s += abuf[(((size_t)(b * 8 + h) * 128) + rb + r) * 128 + l];
    s *= 0.125f;
    aw[r][l] = s;
    aavg[(size_t)(b * 128 + rb + r) * 128 + l] = s;
  }
  __syncthreads();
  int d = t * 2;
  float2 acc[8] = {};
  for (int l = 0; l < 128; ++l) {
    float2 e = *(const float2*)&emo[(size_t)(b * 128 + l) * 512 + d];
#pragma unroll
    for (int r = 0; r < 8; ++r) { acc[r].x += aw[r][l] * e.x; acc[r].y += aw[r][l] * e.y; }
  }
#pragma unroll
  for (int r = 0; r < 8; ++r) *(float2*)&ctx[(size_t)(b * 128 + rb + r) * 512 + d] = acc[r];
}

// ---------------- fused: p_mix gate + partial-reduce rowsum + single-pass finalize ----------------
__global__ __launch_bounds__(256) void k_softmax_final(
    const bf16* __restrict__ lg, const float* __restrict__ partial,
    const float* __restrict__ hid, const float* __restrict__ ctx, const float* __restrict__ emb,
    const float* __restrict__ pgw, const float* __restrict__ pgb,
    float* __restrict__ pmix_out, float* __restrict__ pgen, float* __restrict__ pw,
    float* __restrict__ pcopy) {
  __shared__ float red[8];
  int row = blockIdx.x;
  int t = threadIdx.x, lane = t & 63, wid = t >> 6;
  // gate dot partial
  float s;
  {
    int d = t * 2;
    float2 h2 = *(const float2*)&hid[(size_t)row * 512 + d];
    float2 c2 = *(const float2*)&ctx[(size_t)row * 512 + d];
    float2 e2 = *(const float2*)&emb[(size_t)row * 512 + d];
    float2 g0 = *(const float2*)&pgw[d];
    float2 g1 = *(const float2*)&pgw[512 + d];
    float2 g2 = *(const float2*)&pgw[1024 + d];
    s = h2.x*g0.x + h2.y*g0.y + c2.x*g1.x + c2.y*g1.y + e2.x*g2.x + e2.y*g2.y;
  }
  // rowsum partial (250 col-tile contributions)
  float rs = (t < 250) ? partial[(size_t)row * 256 + t] : 0.f;
#pragma unroll
  for (int o = 32; o; o >>= 1) { s += __shfl_xor(s, o); rs += __shfl_xor(rs, o); }
  if (lane == 0) { red[wid] = s; red[4 + wid] = rs; }
  __syncthreads();
  s  = red[0] + red[1] + red[2] + red[3];
  rs = red[4] + red[5] + red[6] + red[7];
  float pm = 1.f / (1.f + __expf(-(s + pgb[0])));
  if (t == 0) pmix_out[row] = pm;
  float inv = 1.f / rs;
  const bf16* L = lg + (size_t)row * 32000;
  float* pgen_r  = pgen  + (size_t)row * 32100;
  float* pw_r    = pw    + (size_t)row * 32100;
  float* pcopy_r = pcopy + (size_t)row * 32100;
  float4 z = {0.f, 0.f, 0.f, 0.f};
  for (int i = t; i < 4000; i += 256) {
    short8 v = *(const short8*)(L + i * 8);
    float p[8];
#pragma unroll
    for (int c = 0; c < 8; ++c) p[c] = __expf(b2f((unsigned short)v[c])) * inv;
    float4 a0 = {p[0], p[1], p[2], p[3]};
    float4 a1 = {p[4], p[5], p[6], p[7]};
    *(float4*)&pgen_r[i * 8]     = a0;
    *(float4*)&pgen_r[i * 8 + 4] = a1;
    float4 w0 = {pm * p[0], pm * p[1], pm * p[2], pm * p[3]};
    float4 w1 = {pm * p[4], pm * p[5], pm * p[6], pm * p[7]};
    *(float4*)&pw_r[i * 8]     = w0;
    *(float4*)&pw_r[i * 8 + 4] = w1;
    *(float4*)&pcopy_r[i * 8]     = z;
    *(float4*)&pcopy_r[i * 8 + 4] = z;
  }
  if (t < 25) {   // pad cols 32000..32099
    int c = 32000 + t * 4;
    *(float4*)&pgen_r[c] = z; *(float4*)&pw_r[c] = z; *(float4*)&pcopy_r[c] = z;
  }
}

// ---------------- scatter copy-distribution (separate dispatch after finalize) ----------------
__global__ __launch_bounds__(256) void k_scatter(const int* __restrict__ src, const float* __restrict__ aavg,
                                                 const float* __restrict__ pmix, float* __restrict__ pw,
                                                 float* __restrict__ pcopy) {
  int tid = blockIdx.x * 256 + threadIdx.x;   // 16384
  int row = tid >> 4, slot = tid & 15;
  int b = row >> 7;
  float qg = 1.f - pmix[row];
#pragma unroll
  for (int i = 0; i < 8; ++i) {
    int l = slot * 8 + i;
    int c = src[b * 128 + l];
    float w = aavg[(size_t)row * 128 + l];
    atomicAdd(&pcopy[(size_t)row * 32100 + c], w);
    atomicAdd(&pw[(size_t)row * 32100 + c], qg * w);
  }
}

// ================= host launch =================
extern "C" void kernel_launch(void* const* d_in, const int* in_sizes, int n_in,
                              void* d_out, int out_size, void* d_ws, size_t ws_size,
                              hipStream_t stream) {
  const int*   ids      = (const int*)d_in[0];
  const float* emo      = (const float*)d_in[1];
  const int*   src      = (const int*)d_in[2];
  const float* tok      = (const float*)d_in[4];
  const float* pos      = (const float*)d_in[5];
  const float* sa_in_w  = (const float*)d_in[6];
  const float* sa_in_b  = (const float*)d_in[7];
  const float* sa_out_w = (const float*)d_in[8];
  const float* sa_out_b = (const float*)d_in[9];
  const float* ca_in_w  = (const float*)d_in[10];
  const float* ca_in_b  = (const float*)d_in[11];
  const float* ca_out_w = (const float*)d_in[12];
  const float* ca_out_b = (const float*)d_in[13];
  const float* w1       = (const float*)d_in[14];
  const float* b1       = (const float*)d_in[15];
  const float* w2       = (const float*)d_in[16];
  const float* b2       = (const float*)d_in[17];
  const float* n1g      = (const float*)d_in[18];
  const float* n1b      = (const float*)d_in[19];
  const float* n2g      = (const float*)d_in[20];
  const float* n2b      = (const float*)d_in[21];
  const float* n3g      = (const float*)d_in[22];
  const float* n3b      = (const float*)d_in[23];
  const float* vpw      = (const float*)d_in[24];
  const float* vpb      = (const float*)d_in[25];
  const float* pgw      = (const float*)d_in[26];
  const float* pgb      = (const float*)d_in[27];
  (void)in_sizes; (void)n_in; (void)out_size; (void)ws_size;

  // output regions (floats)
  constexpr size_t NR = 1024;
  float* out     = (float*)d_out;
  float* o_pw    = out;
  float* o_pgen  = out + NR * 32100;
  float* o_pcopy = out + 2 * NR * 32100;
  float* o_pmix  = out + 3 * NR * 32100;
  float* o_hid   = o_pmix + NR;
  float* o_aavg  = o_hid + NR * 512;
  float* o_ctx   = o_aavg + NR * 128;

  // workspace layout
  char* wp = (char*)d_ws;
  size_t off = 0;
  auto alloc = [&](size_t bytes) { char* r = wp + off; off += (bytes + 255) & ~(size_t)255; return r; };
  bf16*  sa_in_bf  = (bf16*)alloc(3 * 512 * 512 * 2);
  bf16*  sa_out_bf = (bf16*)alloc(512 * 512 * 2);
  bf16*  ca_in_bf  = (bf16*)alloc(3 * 512 * 512 * 2);
  bf16*  ca_out_bf = (bf16*)alloc(512 * 512 * 2);
  bf16*  w1_bf     = (bf16*)alloc(2048 * 512 * 2);
  bf16*  w2_bf     = (bf16*)alloc(2048 * 512 * 2);
  bf16*  vp_bf     = (bf16*)alloc((size_t)32000 * 512 * 2);
  bf16*  emo_bf    = (bf16*)alloc(8 * 128 * 512 * 2);
  float* x         = (float*)alloc(1024 * 512 * 4);
  float* embf      = (float*)alloc(1024 * 512 * 4);
  bf16*  hbf       = (bf16*)alloc(1024 * 512 * 2);
  float* qkv       = (float*)alloc(1024 * 1536 * 4);
  bf16*  aout_bf   = (bf16*)alloc(1024 * 512 * 2);
  float* qca       = (float*)alloc(1024 * 512 * 4);
  float* kvca      = (float*)alloc(1024 * 1024 * 4);
  float* abuf      = (float*)alloc((size_t)8 * 8 * 128 * 128 * 4);
  bf16*  f1bf      = (bf16*)alloc(1024 * 2048 * 2);
  bf16*  hid_bf    = (bf16*)alloc(1024 * 512 * 2);
  bf16*  logits_bf = (bf16*)alloc((size_t)1024 * 32000 * 2);
  float* partial   = (float*)alloc((size_t)1024 * 256 * 4);

  // 1. all casts (one kernel)
  k_cast_all<<<4608, 256, 0, stream>>>(vpw, vp_bf,
                                       sa_in_w, sa_in_bf, sa_out_w, sa_out_bf,
                                       ca_in_w, ca_in_bf, ca_out_w, ca_out_bf,
                                       w1, w1_bf, w2, w2_bf, emo, emo_bf);

  // 2. embedding + LN1 (fused)
  k_embed_ln<<<256, 256, 0, stream>>>(ids, tok, pos, n1g, n1b, x, embf, hbf);

  // 3-5. self-attention block
  k_gemm<0,0,0,0,0,0><<<dim3(12, 8), 256, 0, stream>>>(hbf, sa_in_bf, sa_in_b, nullptr, qkv, nullptr, nullptr, 512, 1536);
  k_attn<1,0><<<dim3(64, 4), 256, 0, stream>>>(qkv, 1536, qkv + 512, 1536, qkv + 1024, 1536,
                                               nullptr, aout_bf, 512);
  k_gemm<0,1,0,0,0,0><<<dim3(4, 8), 256, 0, stream>>>(aout_bf, sa_out_bf, sa_out_b, x, x, nullptr, nullptr, 512, 512);

  // 6-11. cross-attention block
  k_ln<<<256, 256, 0, stream>>>(x, n2g, n2b, hbf);
  k_gemm<0,0,0,0,0,0><<<dim3(4, 8), 256, 0, stream>>>(hbf, ca_in_bf, ca_in_b, nullptr, qca, nullptr, nullptr, 512, 512);
  k_gemm<0,0,0,0,0,0><<<dim3(8, 8), 256, 0, stream>>>(emo_bf, ca_in_bf + 512 * 512, ca_in_b + 512,
                                                      nullptr, kvca, nullptr, nullptr, 512, 1024);
  k_attn<0,1><<<dim3(64, 4), 256, 0, stream>>>(qca, 512, kvca, 1024, kvca + 512, 1024,
                                               abuf, aout_bf, 512);
  k_ctx2<<<dim3(8, 16), 256, 0, stream>>>(abuf, emo, o_aavg, o_ctx);
  k_gemm<0,1,0,0,0,0><<<dim3(4, 8), 256, 0, stream>>>(aout_bf, ca_out_bf, ca_out_b, x, x, nullptr, nullptr, 512, 512);

  // 12-14. FFN (ffn2 fused with hidden fp32+bf16 output)
  k_ln<<<256, 256, 0, stream>>>(x, n3g, n3b, hbf);
  k_gemm<1,0,1,0,0,0><<<dim3(16, 8), 256, 0, stream>>>(hbf, w1_bf, b1, nullptr, f1bf, nullptr, nullptr, 512, 2048);
  k_gemm<0,1,0,0,1,0><<<dim3(4, 8), 256, 0, stream>>>(f1bf, w2_bf, b2, x, o_hid, hid_bf, nullptr, 2048, 512);

  // 15. vocab projection (bf16 B, XCD-swizzled grid) + non-atomic per-tile expsum partials
  k_gemm<0,0,1,1,0,1><<<dim3(8, 250), 256, 0, stream>>>(hid_bf, vp_bf, vpb, nullptr, logits_bf, nullptr, partial, 512, 32000);

  // 16. gate + rowsum reduce + single-pass finalize
  k_softmax_final<<<1024, 256, 0, stream>>>(logits_bf, partial, o_hid, o_ctx, embf, pgw, pgb,
                                            o_pmix, o_pgen, o_pw, o_pcopy);

  // 17. scatter
  k_scatter<<<64, 256, 0, stream>>>(src, o_aavg, o_pmix, o_pw, o_pcopy);
}

// Round 10
// 443.872 us; speedup vs baseline: 1.0575x; 1.0217x over previous
//
#include <hip/hip_runtime.h>
#include <hip/hip_bf16.h>

using bf16   = __hip_bfloat16;
using bf16x8 = __attribute__((ext_vector_type(8))) __bf16;
using f32x4  = __attribute__((ext_vector_type(4))) float;
using short8 = __attribute__((ext_vector_type(8))) short;

__device__ __forceinline__ unsigned short f2b(float x) {
  union { bf16 b; unsigned short u; } t; t.b = __float2bfloat16(x); return t.u;
}
__device__ __forceinline__ float b2f(unsigned short u) {
  union { unsigned int i; float f; } t; t.i = ((unsigned int)u) << 16; return t.f;
}

typedef __attribute__((address_space(1))) const unsigned int* gas1_t;
typedef __attribute__((address_space(3))) unsigned int* las3_t;
__device__ __forceinline__ void gload16(const void* g, void* l) {
  __builtin_amdgcn_global_load_lds((gas1_t)g, (las3_t)l, 16, 0, 0);
}

// ---------------- all f32->bf16 casts in one grid-stride kernel ----------------
__global__ __launch_bounds__(256) void k_cast_all(
    const float* __restrict__ vpsrc, bf16* __restrict__ vpdst,      // 4096000 f4
    const float* __restrict__ s0, bf16* __restrict__ d0,            // sa_in 196608
    const float* __restrict__ s1, bf16* __restrict__ d1,            // sa_out 65536
    const float* __restrict__ s2, bf16* __restrict__ d2,            // ca_in 196608
    const float* __restrict__ s3, bf16* __restrict__ d3,            // ca_out 65536
    const float* __restrict__ s4, bf16* __restrict__ d4,            // w1 262144
    const float* __restrict__ s5, bf16* __restrict__ d5,            // w2 262144
    const float* __restrict__ s6, bf16* __restrict__ d6) {          // emo 131072
  int i = blockIdx.x * 256 + threadIdx.x;
  int str = gridDim.x * 256;
  for (; i < 5275648; i += str) {
    if (i < 4096000) {
      float4 v = ((const float4*)vpsrc)[i];
      ushort4 u; u.x = f2b(v.x); u.y = f2b(v.y); u.z = f2b(v.z); u.w = f2b(v.w);
      ((ushort4*)vpdst)[i] = u;
    } else {
      int j = i - 4096000;
      const float* s; bf16* d; int off;
      if      (j <  196608) { s = s0; d = d0; off = j; }
      else if (j <  262144) { s = s1; d = d1; off = j - 196608; }
      else if (j <  458752) { s = s2; d = d2; off = j - 262144; }
      else if (j <  524288) { s = s3; d = d3; off = j - 458752; }
      else if (j <  786432) { s = s4; d = d4; off = j - 524288; }
      else if (j < 1048576) { s = s5; d = d5; off = j - 786432; }
      else                  { s = s6; d = d6; off = j - 1048576; }
      float4 v = ((const float4*)s)[off];
      ushort4 u; u.x = f2b(v.x); u.y = f2b(v.y); u.z = f2b(v.z); u.w = f2b(v.w);
      ((ushort4*)d)[off] = u;
    }
  }
}

// ---------------- fused token+pos embedding + LayerNorm1 ----------------
__global__ __launch_bounds__(256) void k_embed_ln(const int* __restrict__ ids, const float* __restrict__ tok,
                                                  const float* __restrict__ pos, const float* __restrict__ g,
                                                  const float* __restrict__ bb, float* __restrict__ x,
                                                  float* __restrict__ emb, bf16* __restrict__ o) {
  int wid = threadIdx.x >> 6, lane = threadIdx.x & 63;
  int row = blockIdx.x * 4 + wid;
  int tt = row & 127;
  int id = ids[row];
  int d = lane * 8;
  float4 e0 = *(const float4*)&tok[(size_t)id * 512 + d];
  float4 e1 = *(const float4*)&tok[(size_t)id * 512 + d + 4];
  float4 p0 = *(const float4*)&pos[(size_t)tt * 512 + d];
  float4 p1 = *(const float4*)&pos[(size_t)tt * 512 + d + 4];
  *(float4*)&emb[(size_t)row * 512 + d]     = e0;
  *(float4*)&emb[(size_t)row * 512 + d + 4] = e1;
  float4 v0; v0.x = e0.x + p0.x; v0.y = e0.y + p0.y; v0.z = e0.z + p0.z; v0.w = e0.w + p0.w;
  float4 v1; v1.x = e1.x + p1.x; v1.y = e1.y + p1.y; v1.z = e1.z + p1.z; v1.w = e1.w + p1.w;
  *(float4*)&x[(size_t)row * 512 + d]     = v0;
  *(float4*)&x[(size_t)row * 512 + d + 4] = v1;
  float s = v0.x + v0.y + v0.z + v0.w + v1.x + v1.y + v1.z + v1.w;
  float q = v0.x*v0.x + v0.y*v0.y + v0.z*v0.z + v0.w*v0.w
          + v1.x*v1.x + v1.y*v1.y + v1.z*v1.z + v1.w*v1.w;
#pragma unroll
  for (int t = 32; t; t >>= 1) { s += __shfl_xor(s, t); q += __shfl_xor(q, t); }
  float mean = s * (1.f / 512.f);
  float var  = q * (1.f / 512.f) - mean * mean;
  float rstd = rsqrtf(var + 1e-5f);
  float4 g0 = *(const float4*)&g[d],  g1 = *(const float4*)&g[d + 4];
  float4 b0 = *(const float4*)&bb[d], b1 = *(const float4*)&bb[d + 4];
  short8 pk;
  pk[0] = (short)f2b((v0.x - mean) * rstd * g0.x + b0.x);
  pk[1] = (short)f2b((v0.y - mean) * rstd * g0.y + b0.y);
  pk[2] = (short)f2b((v0.z - mean) * rstd * g0.z + b0.z);
  pk[3] = (short)f2b((v0.w - mean) * rstd * g0.w + b0.w);
  pk[4] = (short)f2b((v1.x - mean) * rstd * g1.x + b1.x);
  pk[5] = (short)f2b((v1.y - mean) * rstd * g1.y + b1.y);
  pk[6] = (short)f2b((v1.z - mean) * rstd * g1.z + b1.z);
  pk[7] = (short)f2b((v1.w - mean) * rstd * g1.w + b1.w);
  *(short8*)&o[(size_t)row * 512 + d] = pk;
}

// ---------------- LayerNorm (fp32 in) -> bf16 out ----------------
__global__ __launch_bounds__(256) void k_ln(const float* __restrict__ x, const float* __restrict__ g,
                                            const float* __restrict__ bb, bf16* __restrict__ o) {
  int wid = threadIdx.x >> 6, lane = threadIdx.x & 63;
  int row = blockIdx.x * 4 + wid;
  const float* xr = x + (size_t)row * 512;
  int d = lane * 8;
  float4 v0 = *(const float4*)&xr[d];
  float4 v1 = *(const float4*)&xr[d + 4];
  float s = v0.x + v0.y + v0.z + v0.w + v1.x + v1.y + v1.z + v1.w;
  float q = v0.x*v0.x + v0.y*v0.y + v0.z*v0.z + v0.w*v0.w
          + v1.x*v1.x + v1.y*v1.y + v1.z*v1.z + v1.w*v1.w;
#pragma unroll
  for (int t = 32; t; t >>= 1) { s += __shfl_xor(s, t); q += __shfl_xor(q, t); }
  float mean = s * (1.f / 512.f);
  float var  = q * (1.f / 512.f) - mean * mean;
  float rstd = rsqrtf(var + 1e-5f);
  float4 g0 = *(const float4*)&g[d],  g1 = *(const float4*)&g[d + 4];
  float4 b0 = *(const float4*)&bb[d], b1 = *(const float4*)&bb[d + 4];
  short8 pk;
  pk[0] = (short)f2b((v0.x - mean) * rstd * g0.x + b0.x);
  pk[1] = (short)f2b((v0.y - mean) * rstd * g0.y + b0.y);
  pk[2] = (short)f2b((v0.z - mean) * rstd * g0.z + b0.z);
  pk[3] = (short)f2b((v0.w - mean) * rstd * g0.w + b0.w);
  pk[4] = (short)f2b((v1.x - mean) * rstd * g1.x + b1.x);
  pk[5] = (short)f2b((v1.y - mean) * rstd * g1.y + b1.y);
  pk[6] = (short)f2b((v1.z - mean) * rstd * g1.z + b1.z);
  pk[7] = (short)f2b((v1.w - mean) * rstd * g1.w + b1.w);
  *(short8*)&o[(size_t)row * 512 + d] = pk;
}

// ---------------- m97-structure bf16 MFMA GEMM with LDS-bounce epilogue ----------------
// SWZ: vp-specific grid mapping (gridDim=(8,250), M-fastest + XCD swizzle).
// HID: write fp32 to Cout AND bf16 to hidb (ffn2 hidden output).
template<int RELU, int RESID, int OUTBF, int SWZ, int HID>
__global__ __launch_bounds__(256) void k_gemm(const bf16* __restrict__ A, const bf16* __restrict__ Wt,
                                              const float* __restrict__ bias, const float* __restrict__ resid,
                                              void* __restrict__ Cout, bf16* __restrict__ hidb,
                                              int K, int ldc) {
  __shared__ __align__(16) float cst[32 * 132];     // 16896 B; aliases Al/Bl during K-loop
  bf16* Al = (bf16*)cst;                            // [128*32]
  bf16* Bl = (bf16*)cst + 4096;                     // [128*32]
  int t = threadIdx.x;
  int lane = t & 63;
  int wid = t >> 6;
  int wr = wid >> 1, wc = wid & 1;
  int trow, tcol;
  if (SWZ) {
    int bid = blockIdx.y * gridDim.x + blockIdx.x;  // gridDim=(8,250)
    int swz = (bid & 7) * 250 + (bid >> 3);         // XCD k owns a contiguous 250-block chunk
    trow = (swz & 7) * 128;
    tcol = (swz >> 3) * 128;
  } else {
    trow = blockIdx.y * 128; tcol = blockIdx.x * 128;
  }
  f32x4 acc[4][4] = {};
  const int kh = (lane >> 4) * 8;      // k-offset within 32
  const int rl = lane & 15;            // fragment row/col
  const int srow = lane >> 2;          // staging: row within 16-row chunk
  const int scol = (lane & 3) * 8;     // staging: k-offset (8 bf16 = 16B)
  for (int kt = 0; kt < K; kt += 32) {
    __syncthreads();
#pragma unroll
    for (int s = 0; s < 2; ++s) {
      int c = wid * 2 + s;             // chunk 0..7 (16 rows each)
      int row = c * 16 + srow;
      gload16(A  + (size_t)(trow + row) * K + kt + scol, &Al[c * 512]);
      gload16(Wt + (size_t)(tcol + row) * K + kt + scol, &Bl[c * 512]);
    }
    __syncthreads();
    bf16x8 af[4], bg[4];
#pragma unroll
    for (int m = 0; m < 4; ++m) af[m] = *(const bf16x8*)&Al[(wr * 64 + m * 16 + rl) * 32 + kh];
#pragma unroll
    for (int n = 0; n < 4; ++n) bg[n] = *(const bf16x8*)&Bl[(wc * 64 + n * 16 + rl) * 32 + kh];
#pragma unroll
    for (int m = 0; m < 4; ++m)
#pragma unroll
      for (int n = 0; n < 4; ++n)
        acc[m][n] = __builtin_amdgcn_mfma_f32_16x16x32_bf16(af[m], bg[n], acc[m][n], 0, 0, 0);
  }
  // ---- epilogue: LDS bounce, coalesced stores ----
  const int s   = t >> 3;              // 0..31 staging row
  const int seg = (t & 7) * 16;        // 0..112 col segment
  float bv[16];
#pragma unroll
  for (int q = 0; q < 16; q += 4) *(float4*)&bv[q] = *(const float4*)&bias[tcol + seg + q];
#pragma unroll
  for (int m = 0; m < 4; ++m) {
    __syncthreads();
#pragma unroll
    for (int n = 0; n < 4; ++n) {
      int col = wc * 64 + n * 16 + rl;
#pragma unroll
      for (int j = 0; j < 4; ++j) {
        int sr = wr * 16 + (lane >> 4) * 4 + j;
        cst[sr * 132 + col] = acc[m][n][j];
      }
    }
    __syncthreads();
    int grow = trow + m * 16 + (s < 16 ? s : 48 + s);   // s>=16 -> row block +64
    size_t base = (size_t)grow * ldc + tcol + seg;
    float v[16];
#pragma unroll
    for (int q = 0; q < 16; q += 4) {
      float4 f = *(float4*)&cst[s * 132 + seg + q];
      v[q] = f.x; v[q+1] = f.y; v[q+2] = f.z; v[q+3] = f.w;
    }
    if (RESID) {
#pragma unroll
      for (int q = 0; q < 16; q += 4) {
        float4 r = *(const float4*)&resid[base + q];
        v[q] += r.x; v[q+1] += r.y; v[q+2] += r.z; v[q+3] += r.w;
      }
    }
#pragma unroll
    for (int q = 0; q < 16; ++q) {
      float val = v[q] + bv[q];
      if (RELU) val = fmaxf(val, 0.f);
      v[q] = val;
    }
    if (OUTBF) {
      short8 p0, p1;
#pragma unroll
      for (int q = 0; q < 8; ++q) { p0[q] = (short)f2b(v[q]); p1[q] = (short)f2b(v[8 + q]); }
      *(short8*)&((bf16*)Cout)[base]     = p0;
      *(short8*)&((bf16*)Cout)[base + 8] = p1;
    } else {
#pragma unroll
      for (int q = 0; q < 16; q += 4) {
        float4 o; o.x = v[q]; o.y = v[q+1]; o.z = v[q+2]; o.w = v[q+3];
        *(float4*)&((float*)Cout)[base + q] = o;
      }
      if (HID) {
        short8 p0, p1;
#pragma unroll
        for (int q = 0; q < 8; ++q) { p0[q] = (short)f2b(v[q]); p1[q] = (short)f2b(v[8 + q]); }
        *(short8*)&hidb[base]     = p0;
        *(short8*)&hidb[base + 8] = p1;
      }
    }
  }
}

// ---------------- attention (fp32 math): one block per (b,h), 32 q-rows per block ----------------
template<int MASK, int WPROB>
__global__ __launch_bounds__(256) void k_attn(const float* __restrict__ Qb, int qs,
                                              const float* __restrict__ Kb, int ks,
                                              const float* __restrict__ Vb, int vs,
                                              float* __restrict__ probs, bf16* __restrict__ Ob, int os) {
  __shared__ float KV[128][68];
  __shared__ float Sc[32][132];
  int t = threadIdx.x;
  int bh = blockIdx.x; int b = bh >> 3, h = bh & 7;
  int rb = blockIdx.y * 32;
  int r = t >> 3, sub = t & 7;
  const float* Kp = Kb + (size_t)(b * 128) * ks + h * 64;
  const float* Vp = Vb + (size_t)(b * 128) * vs + h * 64;
  const float* Qp = Qb + (size_t)(b * 128 + rb + r) * qs + h * 64;
  float4 q[16];
#pragma unroll
  for (int i = 0; i < 16; ++i) q[i] = *(const float4*)&Qp[i * 4];
  for (int i = 0; i < 32; ++i) { int u = t + i * 256; int rr = u >> 6, dd = u & 63; KV[rr][dd] = Kp[(size_t)rr * ks + dd]; }
  __syncthreads();
  float sc[16];
#pragma unroll
  for (int i = 0; i < 16; ++i) {
    int c = sub + i * 8;
    float a = 0.f;
#pragma unroll
    for (int d4 = 0; d4 < 16; ++d4) {
      float4 k4 = *(const float4*)&KV[c][d4 * 4];
      a += q[d4].x * k4.x + q[d4].y * k4.y + q[d4].z * k4.z + q[d4].w * k4.w;
    }
    a *= 0.125f;
    if (MASK && c > rb + r) a -= 1e9f;
    sc[i] = a;
  }
  float mx = -1e30f;
#pragma unroll
  for (int i = 0; i < 16; ++i) mx = fmaxf(mx, sc[i]);
  mx = fmaxf(mx, __shfl_xor(mx, 1)); mx = fmaxf(mx, __shfl_xor(mx, 2)); mx = fmaxf(mx, __shfl_xor(mx, 4));
  float sm = 0.f;
#pragma unroll
  for (int i = 0; i < 16; ++i) { sc[i] = __expf(sc[i] - mx); sm += sc[i]; }
  sm += __shfl_xor(sm, 1); sm += __shfl_xor(sm, 2); sm += __shfl_xor(sm, 4);
  float inv = 1.f / sm;
#pragma unroll
  for (int i = 0; i < 16; ++i) {
    float p = sc[i] * inv;
    Sc[r][sub + i * 8] = p;
    if (WPROB) probs[(((size_t)(b * 8 + h) * 128) + rb + r) * 128 + sub + i * 8] = p;
  }
  __syncthreads();
  for (int i = 0; i < 32; ++i) { int u = t + i * 256; int rr = u >> 6, dd = u & 63; KV[rr][dd] = Vp[(size_t)rr * vs + dd]; }
  __syncthreads();
  int dg = sub;
  float4 o0 = {0,0,0,0}, o1 = {0,0,0,0};
  for (int j = 0; j < 128; ++j) {
    float p = Sc[r][j];
    float4 va = *(const float4*)&KV[j][dg * 8];
    float4 vb = *(const float4*)&KV[j][dg * 8 + 4];
    o0.x += p * va.x; o0.y += p * va.y; o0.z += p * va.z; o0.w += p * va.w;
    o1.x += p * vb.x; o1.y += p * vb.y; o1.z += p * vb.z; o1.w += p * vb.w;
  }
  short8 pk;
  pk[0] = (short)f2b(o0.x); pk[1] = (short)f2b(o0.y); pk[2] = (short)f2b(o0.z); pk[3] = (short)f2b(o0.w);
  pk[4] = (short)f2b(o1.x); pk[5] = (short)f2b(o1.y); pk[6] = (short)f2b(o1.z); pk[7] = (short)f2b(o1.w);
  *(short8*)&Ob[(size_t)(b * 128 + rb + r) * os + h * 64 + dg * 8] = pk;
}

// ---------------- fused: attn mean over heads + aavg out + ctx = aavg @ emofused ----------------
__global__ __launch_bounds__(256) void k_ctx2(const float* __restrict__ abuf, const float* __restrict__ emo,
                                              float* __restrict__ aavg, float* __restrict__ ctx) {
  __shared__ float aw[8][132];
  int b = blockIdx.x, rb = blockIdx.y * 8;
  int t = threadIdx.x;
  for (int i = t; i < 1024; i += 256) {
    int r = i >> 7, l = i & 127;
    float s = 0.f;
#pragma unroll
    for (int h = 0; h < 8; ++h) s += abuf[(((size_t)(b * 8 + h) * 128) + rb + r) * 128 + l];
    s *= 0.125f;
    aw[r][l] = s;
    aavg[(size_t)(b * 128 + rb + r) * 128 + l] = s;
  }
  __syncthreads();
  int d = t * 2;
  float2 acc[8] = {};
  for (int l = 0; l < 128; ++l) {
    float2 e = *(const float2*)&emo[(size_t)(b * 128 + l) * 512 + d];
#pragma unroll
    for (int r = 0; r < 8; ++r) { acc[r].x += aw[r][l] * e.x; acc[r].y += aw[r][l] * e.y; }
  }
#pragma unroll
  for (int r = 0; r < 8; ++r) *(float2*)&ctx[(size_t)(b * 128 + rb + r) * 512 + d] = acc[r];
}

// ---------------- hidden: copy to out + bf16 cast is fused into ffn2 GEMM (HID) ----------------

// ---------------- p_mix gate ----------------
__global__ __launch_bounds__(256) void k_gate(const float* __restrict__ hid, const float* __restrict__ ctx,
                                              const float* __restrict__ emb, const float* __restrict__ pgw,
                                              const float* __restrict__ pgb, float* __restrict__ pmix) {
  int wid = threadIdx.x >> 6, lane = threadIdx.x & 63;
  int row = blockIdx.x * 4 + wid;
  float s = 0.f;
#pragma unroll
  for (int i = 0; i < 8; ++i) {
    int d = lane + i * 64;
    s = fmaf(hid[(size_t)row * 512 + d], pgw[d], s);
    s = fmaf(ctx[(size_t)row * 512 + d], pgw[512 + d], s);
    s = fmaf(emb[(size_t)row * 512 + d], pgw[1024 + d], s);
  }
#pragma unroll
  for (int t = 32; t; t >>= 1) s += __shfl_xor(s, t);
  if (lane == 0) pmix[row] = 1.f / (1.f + __expf(-(s + pgb[0])));
}

// ---------------- fused: softmax over bf16 logits + Pgen/Pw/Pcopy(0) writes ----------------
// 2 passes (sum, then write); second logits read is L2-resident. No max-subtraction
// (|logit| small, exp fp32-safe; softmax shift-invariant). Replay-idempotent.
__global__ __launch_bounds__(256) void k_softmax_final(
    const bf16* __restrict__ lg, const float* __restrict__ pmix,
    float* __restrict__ pgen, float* __restrict__ pw, float* __restrict__ pcopy) {
  __shared__ float red[4];
  int row = blockIdx.x;
  int t = threadIdx.x, lane = t & 63, wid = t >> 6;
  const bf16* L = lg + (size_t)row * 32000;
  // pass A: sum of exp
  float s = 0.f;
  for (int i = t; i < 4000; i += 256) {
    short8 v = *(const short8*)(L + i * 8);
#pragma unroll
    for (int c = 0; c < 8; ++c) s += __expf(b2f((unsigned short)v[c]));
  }
#pragma unroll
  for (int o = 32; o; o >>= 1) s += __shfl_xor(s, o);
  if (lane == 0) red[wid] = s;
  __syncthreads();
  s = red[0] + red[1] + red[2] + red[3];
  float inv = 1.f / s;
  float pm = pmix[row];
  float* pgen_r  = pgen  + (size_t)row * 32100;
  float* pw_r    = pw    + (size_t)row * 32100;
  float* pcopy_r = pcopy + (size_t)row * 32100;
  // pass B: write Pgen, Pw = pm*Pgen, Pcopy = 0
  float4 z = {0.f, 0.f, 0.f, 0.f};
  for (int i = t; i < 4000; i += 256) {
    short8 v = *(const short8*)(L + i * 8);
    float p[8];
#pragma unroll
    for (int c = 0; c < 8; ++c) p[c] = __expf(b2f((unsigned short)v[c])) * inv;
    float4 a0 = {p[0], p[1], p[2], p[3]};
    float4 a1 = {p[4], p[5], p[6], p[7]};
    *(float4*)&pgen_r[i * 8]     = a0;
    *(float4*)&pgen_r[i * 8 + 4] = a1;
    float4 w0 = {pm * p[0], pm * p[1], pm * p[2], pm * p[3]};
    float4 w1 = {pm * p[4], pm * p[5], pm * p[6], pm * p[7]};
    *(float4*)&pw_r[i * 8]     = w0;
    *(float4*)&pw_r[i * 8 + 4] = w1;
    *(float4*)&pcopy_r[i * 8]     = z;
    *(float4*)&pcopy_r[i * 8 + 4] = z;
  }
  if (t < 25) {   // pad cols 32000..32099
    int c = 32000 + t * 4;
    *(float4*)&pgen_r[c] = z; *(float4*)&pw_r[c] = z; *(float4*)&pcopy_r[c] = z;
  }
}

// ---------------- scatter copy-distribution (separate dispatch after finalize) ----------------
__global__ __launch_bounds__(256) void k_scatter(const int* __restrict__ src, const float* __restrict__ aavg,
                                                 const float* __restrict__ pmix, float* __restrict__ pw,
                                                 float* __restrict__ pcopy) {
  int tid = blockIdx.x * 256 + threadIdx.x;   // 16384
  int row = tid >> 4, slot = tid & 15;
  int b = row >> 7;
  float qg = 1.f - pmix[row];
#pragma unroll
  for (int i = 0; i < 8; ++i) {
    int l = slot * 8 + i;
    int c = src[b * 128 + l];
    float w = aavg[(size_t)row * 128 + l];
    atomicAdd(&pcopy[(size_t)row * 32100 + c], w);
    atomicAdd(&pw[(size_t)row * 32100 + c], qg * w);
  }
}

// ================= host launch =================
extern "C" void kernel_launch(void* const* d_in, const int* in_sizes, int n_in,
                              void* d_out, int out_size, void* d_ws, size_t ws_size,
                              hipStream_t stream) {
  const int*   ids      = (const int*)d_in[0];
  const float* emo      = (const float*)d_in[1];
  const int*   src      = (const int*)d_in[2];
  const float* tok      = (const float*)d_in[4];
  const float* pos      = (const float*)d_in[5];
  const float* sa_in_w  = (const float*)d_in[6];
  const float* sa_in_b  = (const float*)d_in[7];
  const float* sa_out_w = (const float*)d_in[8];
  const float* sa_out_b = (const float*)d_in[9];
  const float* ca_in_w  = (const float*)d_in[10];
  const float* ca_in_b  = (const float*)d_in[11];
  const float* ca_out_w = (const float*)d_in[12];
  const float* ca_out_b = (const float*)d_in[13];
  const float* w1       = (const float*)d_in[14];
  const float* b1       = (const float*)d_in[15];
  const float* w2       = (const float*)d_in[16];
  const float* b2       = (const float*)d_in[17];
  const float* n1g      = (const float*)d_in[18];
  const float* n1b      = (const float*)d_in[19];
  const float* n2g      = (const float*)d_in[20];
  const float* n2b      = (const float*)d_in[21];
  const float* n3g      = (const float*)d_in[22];
  const float* n3b      = (const float*)d_in[23];
  const float* vpw      = (const float*)d_in[24];
  const float* vpb      = (const float*)d_in[25];
  const float* pgw      = (const float*)d_in[26];
  const float* pgb      = (const float*)d_in[27];
  (void)in_sizes; (void)n_in; (void)out_size; (void)ws_size;

  // output regions (floats)
  constexpr size_t NR = 1024;
  float* out     = (float*)d_out;
  float* o_pw    = out;
  float* o_pgen  = out + NR * 32100;
  float* o_pcopy = out + 2 * NR * 32100;
  float* o_pmix  = out + 3 * NR * 32100;
  float* o_hid   = o_pmix + NR;
  float* o_aavg  = o_hid + NR * 512;
  float* o_ctx   = o_aavg + NR * 128;

  // workspace layout
  char* wp = (char*)d_ws;
  size_t off = 0;
  auto alloc = [&](size_t bytes) { char* r = wp + off; off += (bytes + 255) & ~(size_t)255; return r; };
  bf16*  sa_in_bf  = (bf16*)alloc(3 * 512 * 512 * 2);
  bf16*  sa_out_bf = (bf16*)alloc(512 * 512 * 2);
  bf16*  ca_in_bf  = (bf16*)alloc(3 * 512 * 512 * 2);
  bf16*  ca_out_bf = (bf16*)alloc(512 * 512 * 2);
  bf16*  w1_bf     = (bf16*)alloc(2048 * 512 * 2);
  bf16*  w2_bf     = (bf16*)alloc(2048 * 512 * 2);
  bf16*  vp_bf     = (bf16*)alloc((size_t)32000 * 512 * 2);
  bf16*  emo_bf    = (bf16*)alloc(8 * 128 * 512 * 2);
  float* x         = (float*)alloc(1024 * 512 * 4);
  float* embf      = (float*)alloc(1024 * 512 * 4);
  bf16*  hbf       = (bf16*)alloc(1024 * 512 * 2);
  float* qkv       = (float*)alloc(1024 * 1536 * 4);
  bf16*  aout_bf   = (bf16*)alloc(1024 * 512 * 2);
  float* qca       = (float*)alloc(1024 * 512 * 4);
  float* kvca      = (float*)alloc(1024 * 1024 * 4);
  float* abuf      = (float*)alloc((size_t)8 * 8 * 128 * 128 * 4);
  bf16*  f1bf      = (bf16*)alloc(1024 * 2048 * 2);
  bf16*  hid_bf    = (bf16*)alloc(1024 * 512 * 2);
  bf16*  logits_bf = (bf16*)alloc((size_t)1024 * 32000 * 2);

  // 1. all casts (one kernel)
  k_cast_all<<<4608, 256, 0, stream>>>(vpw, vp_bf,
                                       sa_in_w, sa_in_bf, sa_out_w, sa_out_bf,
                                       ca_in_w, ca_in_bf, ca_out_w, ca_out_bf,
                                       w1, w1_bf, w2, w2_bf, emo, emo_bf);

  // 2. embedding + LN1 (fused)
  k_embed_ln<<<256, 256, 0, stream>>>(ids, tok, pos, n1g, n1b, x, embf, hbf);

  // 3-5. self-attention block
  k_gemm<0,0,0,0,0><<<dim3(12, 8), 256, 0, stream>>>(hbf, sa_in_bf, sa_in_b, nullptr, qkv, nullptr, 512, 1536);
  k_attn<1,0><<<dim3(64, 4), 256, 0, stream>>>(qkv, 1536, qkv + 512, 1536, qkv + 1024, 1536,
                                               nullptr, aout_bf, 512);
  k_gemm<0,1,0,0,0><<<dim3(4, 8), 256, 0, stream>>>(aout_bf, sa_out_bf, sa_out_b, x, x, nullptr, 512, 512);

  // 6-11. cross-attention block
  k_ln<<<256, 256, 0, stream>>>(x, n2g, n2b, hbf);
  k_gemm<0,0,0,0,0><<<dim3(4, 8), 256, 0, stream>>>(hbf, ca_in_bf, ca_in_b, nullptr, qca, nullptr, 512, 512);
  k_gemm<0,0,0,0,0><<<dim3(8, 8), 256, 0, stream>>>(emo_bf, ca_in_bf + 512 * 512, ca_in_b + 512,
                                                    nullptr, kvca, nullptr, 512, 1024);
  k_attn<0,1><<<dim3(64, 4), 256, 0, stream>>>(qca, 512, kvca, 1024, kvca + 512, 1024,
                                               abuf, aout_bf, 512);
  k_ctx2<<<dim3(8, 16), 256, 0, stream>>>(abuf, emo, o_aavg, o_ctx);
  k_gemm<0,1,0,0,0><<<dim3(4, 8), 256, 0, stream>>>(aout_bf, ca_out_bf, ca_out_b, x, x, nullptr, 512, 512);

  // 12-14. FFN (ffn2 fused with hidden fp32+bf16 output)
  k_ln<<<256, 256, 0, stream>>>(x, n3g, n3b, hbf);
  k_gemm<1,0,1,0,0><<<dim3(16, 8), 256, 0, stream>>>(hbf, w1_bf, b1, nullptr, f1bf, nullptr, 512, 2048);
  k_gemm<0,1,0,0,1><<<dim3(4, 8), 256, 0, stream>>>(f1bf, w2_bf, b2, x, o_hid, hid_bf, 2048, 512);

  // 15. gate
  k_gate<<<256, 256, 0, stream>>>(o_hid, o_ctx, embf, pgw, pgb, o_pmix);

  // 16-18. vocab projection (bf16 logits, M-fastest XCD-swizzled grid) + softmax/final + scatter
  k_gemm<0,0,1,1,0><<<dim3(8, 250), 256, 0, stream>>>(hid_bf, vp_bf, vpb, nullptr, logits_bf, nullptr, 512, 32000);
  k_softmax_final<<<1024, 256, 0, stream>>>(logits_bf, o_pmix, o_pgen, o_pw, o_pcopy);
  k_scatter<<<64, 256, 0, stream>>>(src, o_aavg, o_pmix, o_pw, o_pcopy);
}